// Round 2
// baseline (629.841 us; speedup 1.0000x reference)
//
#include <hip/hip_runtime.h>
#include <hip/hip_bf16.h>

#define N_NODES 50000
#define N_EDGES 800000
#define N_BUCKETS 64
#define M_PAD 50048

// ---- slice-phased aggregation geometry ------------------------------------
#define NS 8                 // source slices
#define SLICE_DIV 6250       // nodes per slice (50000/8)
#define NC (N_NODES * NS)    // 400000 (v,slice) cells
#define AGG_BLOCKS 1024      // persistent blocks (4 waves each)
#define NWAVES (AGG_BLOCKS * 4)
#define DPW 13               // dests per wave: 4096*13 = 53248 >= 50000
#define CELL_NB ((NC + 255) / 256)   // 1563

typedef short short8 __attribute__((ext_vector_type(8)));
typedef float floatx4 __attribute__((ext_vector_type(4)));
typedef float floatx2 __attribute__((ext_vector_type(2)));

// ---- bf16 helpers (RNE) ---------------------------------------------------
__device__ __forceinline__ unsigned short f2bf(float f) {
    unsigned u = __float_as_uint(f);
    unsigned r = (u + 0x7fff + ((u >> 16) & 1)) >> 16;
    return (unsigned short)r;
}
__device__ __forceinline__ float bf2f(unsigned short h) {
    return __uint_as_float(((unsigned)h) << 16);
}
__device__ __forceinline__ void expand2(unsigned u, float& lo, float& hi) {
    lo = __uint_as_float(u << 16);
    hi = __uint_as_float(u & 0xffff0000u);
}

// ---- fp8 e4m3 (OCP) HW conversion helpers ---------------------------------
__device__ __forceinline__ unsigned pack4_fp8(float f0, float f1, float f2, float f3) {
    int v = __builtin_amdgcn_cvt_pk_fp8_f32(f0, f1, 0, false);
    v = __builtin_amdgcn_cvt_pk_fp8_f32(f2, f3, v, true);
    return (unsigned)v;
}
__device__ __forceinline__ void accum_fp8x4(float* a, unsigned u, float w) {
    floatx2 lo = __builtin_amdgcn_cvt_pk_f32_fp8((int)u, false);
    floatx2 hi = __builtin_amdgcn_cvt_pk_f32_fp8((int)u, true);
    a[0] += lo[0] * w; a[1] += lo[1] * w;
    a[2] += hi[0] * w; a[3] += hi[1] * w;
}
__device__ __forceinline__ void accum_fp8x2(float* a, unsigned u, float w) {
    floatx2 lo = __builtin_amdgcn_cvt_pk_f32_fp8((int)u, false);
    a[0] += lo[0] * w; a[1] += lo[1] * w;
}

// async global->LDS, 16B per lane (GEMM staging)
__device__ __forceinline__ void gload16(const void* gp, void* lp) {
    __builtin_amdgcn_global_load_lds(
        (const __attribute__((address_space(1))) unsigned int*)gp,
        (__attribute__((address_space(3))) unsigned int*)lp,
        16, 0, 0);
}

// ---------------------------------------------------------------------------
// CSR-by-(dest, source-slice) build.
// cnt2[v*NS+s] = #edges into v whose source lies in slice s (incl. self-loop).
__global__ void k_init2(int* __restrict__ cnt2, float* __restrict__ gb) {
    int i = blockIdx.x * blockDim.x + threadIdx.x;
    if (i < NC) cnt2[i] = 0;
    if (i < N_BUCKETS * 256) gb[i] = 0.0f;
}

__global__ void k_count2(const int* __restrict__ row, const int* __restrict__ col,
                         int* __restrict__ cnt2) {
    int e = blockIdx.x * blockDim.x + threadIdx.x;
    if (e >= N_EDGES) return;
    int s = row[e] / SLICE_DIV;
    atomicAdd(&cnt2[col[e] * NS + s], 1);
}

__global__ void k_self(int* __restrict__ cnt2) {
    int i = blockIdx.x * blockDim.x + threadIdx.x;
    if (i < N_NODES) atomicAdd(&cnt2[i * NS + i / SLICE_DIV], 1);
}

// dinv from total (incl. self) degree; runs after k_count2 + k_self
__global__ void k_dinv(const int* __restrict__ cnt2, float* __restrict__ dinv) {
    int i = blockIdx.x * blockDim.x + threadIdx.x;
    if (i >= N_NODES) return;
    const int4* c4 = (const int4*)&cnt2[i * NS];
    int4 a = c4[0], b = c4[1];
    int c = a.x + a.y + a.z + a.w + b.x + b.y + b.z + b.w;
    dinv[i] = 1.0f / sqrtf((float)c);
}

// 3-level exclusive scan over the NC=400000 cell counts
__global__ __launch_bounds__(256) void k_scanA2(const int* __restrict__ cnt2,
                                                int* __restrict__ bsum) {
    __shared__ int red[256];
    int t = threadIdx.x;
    int i = blockIdx.x * 256 + t;
    red[t] = (i < NC) ? cnt2[i] : 0;
    __syncthreads();
    for (int d = 128; d > 0; d >>= 1) {
        if (t < d) red[t] += red[t + d];
        __syncthreads();
    }
    if (t == 0) bsum[blockIdx.x] = red[0];
}

// single-block sequential-chunk scan over CELL_NB (=1563) partial sums
__global__ __launch_bounds__(256) void k_scanB2(const int* __restrict__ bsum,
                                                int* __restrict__ bbase) {
    __shared__ int sc[256];
    __shared__ int carry;
    int t = threadIdx.x;
    if (t == 0) carry = 0;
    __syncthreads();
    for (int base = 0; base < CELL_NB; base += 256) {
        int idx = base + t;
        int v = (idx < CELL_NB) ? bsum[idx] : 0;
        sc[t] = v;
        __syncthreads();
        for (int d = 1; d < 256; d <<= 1) {
            int x = 0;
            if (t >= d) x = sc[t - d];
            __syncthreads();
            if (t >= d) sc[t] += x;
            __syncthreads();
        }
        if (idx < CELL_NB) bbase[idx] = carry + sc[t] - v;  // exclusive
        __syncthreads();
        if (t == 255) carry += sc[255];
        __syncthreads();
    }
}

__global__ __launch_bounds__(256) void k_scanC2(const int* __restrict__ cnt2,
                                                const int* __restrict__ bbase,
                                                int* __restrict__ off2,
                                                int* __restrict__ cursor2) {
    __shared__ int sc[256];
    int t = threadIdx.x;
    int i = blockIdx.x * 256 + t;
    int c = (i < NC) ? cnt2[i] : 0;
    sc[t] = c;
    __syncthreads();
    for (int d = 1; d < 256; d <<= 1) {
        int v = 0;
        if (t >= d) v = sc[t - d];
        __syncthreads();
        if (t >= d) sc[t] += v;
        __syncthreads();
    }
    if (i < NC) {
        int o = sc[t] - c + bbase[blockIdx.x];
        off2[i] = o;
        cursor2[i] = o;
        if (i == NC - 1) off2[NC] = o + c;   // sentinel = E + N
    }
}

__global__ void k_fill2(const int* __restrict__ row, const int* __restrict__ col,
                        const float* __restrict__ dinv, int* __restrict__ cursor2,
                        int2* __restrict__ epack) {
    int e = blockIdx.x * blockDim.x + threadIdx.x;
    if (e >= N_EDGES) return;
    int r = row[e];
    int v = col[e];
    int s = r / SLICE_DIV;
    int p = atomicAdd(&cursor2[v * NS + s], 1);
    epack[p] = make_int2(r, __float_as_int(dinv[r]));
}

__global__ void k_fillself(const float* __restrict__ dinv, int* __restrict__ cursor2,
                           int2* __restrict__ epack) {
    int i = blockIdx.x * blockDim.x + threadIdx.x;
    if (i >= N_NODES) return;
    int p = atomicAdd(&cursor2[i * NS + i / SLICE_DIV], 1);
    epack[p] = make_int2(i, __float_as_int(dinv[i]));
}

// W [K][N] fp32 -> transposed split bf16 WT{h,l} [N][K] (weights stay exact)
__global__ void k_prepW(const float* __restrict__ W,
                        unsigned short* __restrict__ Th,
                        unsigned short* __restrict__ Tl, int K, int N) {
    int idx = blockIdx.x * blockDim.x + threadIdx.x;
    if (idx >= K * N) return;
    int n = idx / K, k = idx - n * K;
    float v = W[(size_t)k * N + n];
    unsigned short h = f2bf(v);
    Th[idx] = h;
    Tl[idx] = f2bf(v - bf2f(h));
}

// x fp32 -> fp8 e4m3; one thread per 4 features
__global__ void k_prepX8(const float* __restrict__ x, unsigned char* __restrict__ xq) {
    int i = blockIdx.x * blockDim.x + threadIdx.x;
    if (i >= N_NODES * 32) return;
    const float* s = x + (size_t)i * 4;
    *(unsigned*)&xq[(size_t)i * 4] = pack4_fp8(s[0], s[1], s[2], s[3]);
}

// ---------------------------------------------------------------------------
// Slice-phased persistent aggregation.
// Theory: agg was pinned at ~0.88 TB/s of L2-miss random service (round-0/1
// evidence: quadrupling per-wave MLP was exactly neutral; DIM=128 == DIM=256).
// Fix locality, not concurrency: edges are grouped by source SLICE (1.6 MB of
// the fp8 table per slice at DIM=256); all persistent waves sweep slices in
// the same order, so the live gather working set fits the 4 MB per-XCD L2.
// Phase alignment is statistical (common start + negative feedback: waves
// running ahead hit the cold next slice and slow down); correctness is
// order-independent. Each wave owns DPW dests, accumulators in registers,
// lane layout = 4B (DIM=256) / 2B (DIM=128) of features per lane, so one
// gather instruction = exactly one row. Descriptor/offset loads are
// wave-uniform -> scalar path.
// POOL=0: bf16 rows out (feeds GEMM). POOL=1: bias+relu+bucketed mean-pool.
template <int DIM, int POOL>
__global__ __launch_bounds__(256) void k_aggp(
    const unsigned char* __restrict__ xq, const int* __restrict__ off2,
    const int2* __restrict__ epack, const float* __restrict__ dinv,
    const float* __restrict__ bias, unsigned short* __restrict__ outb,
    float* __restrict__ gb) {
    const int FPL = DIM / 64;   // accum floats per lane per dest: 4 or 2
    const int wv = __builtin_amdgcn_readfirstlane(threadIdx.x >> 6);
    const int li = threadIdx.x & 63;
    const int wid = blockIdx.x * 4 + wv;
    const int d0 = wid * DPW;
    const unsigned char* __restrict__ xl = xq + li * FPL;

    float acc[DPW][FPL];
#pragma unroll
    for (int di = 0; di < DPW; ++di)
#pragma unroll
        for (int i = 0; i < FPL; ++i) acc[di][i] = 0.0f;

    for (int s = 0; s < NS; ++s) {   // slice-major sweep (the locality phase)
#pragma unroll
        for (int di = 0; di < DPW; ++di) {
            int v = d0 + di;
            if (v >= N_NODES) continue;
            int cell = v * NS + s;
            int jb = off2[cell];
            int je = off2[cell + 1];
            for (int j = jb; j < je; ++j) {
                int2 ed = epack[j];                 // wave-uniform
                float w = __int_as_float(ed.y);
                if constexpr (DIM == 256) {
                    unsigned g = *(const unsigned*)&xl[(size_t)ed.x * DIM];
                    accum_fp8x4(acc[di], g, w);
                } else {
                    unsigned g = (unsigned)*(const unsigned short*)&xl[(size_t)ed.x * DIM];
                    accum_fp8x2(acc[di], g, w);
                }
            }
        }
    }

    if constexpr (!POOL) {
#pragma unroll
        for (int di = 0; di < DPW; ++di) {
            int v = d0 + di;
            if (v >= N_NODES) continue;
            float dv = dinv[v];
            if constexpr (DIM == 256) {
                uint2 o;
                o.x = (unsigned)f2bf(acc[di][0] * dv) | ((unsigned)f2bf(acc[di][1] * dv) << 16);
                o.y = (unsigned)f2bf(acc[di][2] * dv) | ((unsigned)f2bf(acc[di][3] * dv) << 16);
                *(uint2*)&outb[(size_t)v * DIM + li * 4] = o;
            } else {
                unsigned o = (unsigned)f2bf(acc[di][0] * dv) | ((unsigned)f2bf(acc[di][1] * dv) << 16);
                *(unsigned*)&outb[(size_t)v * DIM + li * 2] = o;
            }
        }
    } else {
        // DIM == 256 only: relu(acc*dv + b) summed over this wave's dests
        floatx4 bv = *(const floatx4*)&bias[li * 4];
        float ps0 = 0.f, ps1 = 0.f, ps2 = 0.f, ps3 = 0.f;
#pragma unroll
        for (int di = 0; di < DPW; ++di) {
            int v = d0 + di;
            if (v >= N_NODES) continue;
            float dv = dinv[v];
            ps0 += fmaxf(acc[di][0] * dv + bv[0], 0.0f);
            ps1 += fmaxf(acc[di][1] * dv + bv[1], 0.0f);
            ps2 += fmaxf(acc[di][2] * dv + bv[2], 0.0f);
            ps3 += fmaxf(acc[di][3] * dv + bv[3], 0.0f);
        }
        float* g0 = &gb[(wid & (N_BUCKETS - 1)) * 256 + li * 4];
        atomicAdd(g0 + 0, ps0);
        atomicAdd(g0 + 1, ps1);
        atomicAdd(g0 + 2, ps2);
        atomicAdd(g0 + 3, ps3);
    }
}

// ---------------------------------------------------------------------------
// bf16-A x split-bf16-B MFMA GEMM: C = A @ (Bh+Bl) (+bias)(relu)
// B pre-transposed [N][K]. 128x128 tile, BK=32, SINGLE-buffered LDS (32KB ->
// 5 blocks/CU). LDS-staged coalesced epilogue. OUTFP8=1: fp8-e4m3 writeback.
template <int BIAS, int RELU, int OUTFP8>
__global__ __launch_bounds__(256) void k_gemm_b(
    const unsigned short* __restrict__ A,
    const unsigned short* __restrict__ Bh, const unsigned short* __restrict__ Bl,
    const float* __restrict__ bias, void* __restrict__ Cout,
    int M, int K, int N) {
    __shared__ unsigned short smem[4 * 4096];   // 32KB
    unsigned short* As  = smem;                 // 8KB
    unsigned short* BsH = smem + 4096;          // 8KB
    unsigned short* BsL = smem + 8192;          // 8KB
    int tid = threadIdx.x;
    int lane = tid & 63;
    int w = tid >> 6;
    int wr = w & 1, wc = w >> 1;
    int bm = blockIdx.x * 128, bn = blockIdx.y * 128;

    floatx4 acc[4][4];
    floatx4 zero = {0.f, 0.f, 0.f, 0.f};
#pragma unroll
    for (int t = 0; t < 4; ++t)
#pragma unroll
        for (int u = 0; u < 4; ++u) acc[t][u] = zero;

    int c0 = w * 2, c1 = c0 + 1;
    int srow = lane >> 2;
    int kg = ((lane & 3) - ((lane >> 3) & 3)) & 3;
    int kc = kg * 8;
    const unsigned short* Ap0 = A + (size_t)(bm + c0 * 16 + srow) * K + kc;
    const unsigned short* Ap1 = A + (size_t)(bm + c1 * 16 + srow) * K + kc;
    const unsigned short* Bh0 = Bh + (size_t)(bn + c0 * 16 + srow) * K + kc;
    const unsigned short* Bh1 = Bh + (size_t)(bn + c1 * 16 + srow) * K + kc;
    const unsigned short* Bl0 = Bl + (size_t)(bn + c0 * 16 + srow) * K + kc;
    const unsigned short* Bl1 = Bl + (size_t)(bn + c1 * 16 + srow) * K + kc;

    const int KT = K >> 5;
    int fr = lane & 15;
    int fq = lane >> 4;
    int cl = ((fq + (fr >> 1)) & 3) * 8;

    for (int kt = 0; kt < KT; ++kt) {
        int k0 = kt * 32;
        gload16(Ap0 + k0, As + c0 * 512);
        gload16(Ap1 + k0, As + c1 * 512);
        gload16(Bh0 + k0, BsH + c0 * 512);
        gload16(Bh1 + k0, BsH + c1 * 512);
        gload16(Bl0 + k0, BsL + c0 * 512);
        gload16(Bl1 + k0, BsL + c1 * 512);
        __syncthreads();
        short8 av[4], bhv[4], blv[4];
#pragma unroll
        for (int t = 0; t < 4; ++t) {
            av[t]  = *(const short8*)&As[(wr * 64 + t * 16 + fr) * 32 + cl];
            bhv[t] = *(const short8*)&BsH[(wc * 64 + t * 16 + fr) * 32 + cl];
            blv[t] = *(const short8*)&BsL[(wc * 64 + t * 16 + fr) * 32 + cl];
        }
#pragma unroll
        for (int t = 0; t < 4; ++t)
#pragma unroll
            for (int u = 0; u < 4; ++u) {
                acc[t][u] = __builtin_amdgcn_mfma_f32_16x16x32_bf16(av[t], bhv[u], acc[t][u], 0, 0, 0);
                acc[t][u] = __builtin_amdgcn_mfma_f32_16x16x32_bf16(av[t], blv[u], acc[t][u], 0, 0, 0);
            }
        __syncthreads();
    }

    // ---- LDS-staged epilogue (reuses all 32KB) ----
    unsigned short* cq = smem + w * 4096;
#pragma unroll
    for (int u = 0; u < 4; ++u) {
        int colq = u * 16 + fr;
        float bv = BIAS ? bias[bn + wc * 64 + colq] : 0.0f;
#pragma unroll
        for (int t = 0; t < 4; ++t) {
#pragma unroll
            for (int r = 0; r < 4; ++r) {
                float o = acc[t][u][r] + bv;
                if (RELU) o = fmaxf(o, 0.f);
                cq[(t * 16 + fq * 4 + r) * 64 + colq] = f2bf(o);
            }
        }
    }
    __syncthreads();
    int lr = tid >> 4;
    int lc = (tid & 15) * 8;
    int wcq = lc >> 6;
    int lcq = lc & 63;
#pragma unroll
    for (int i = 0; i < 8; ++i) {
        int rowt = i * 16 + lr;
        int wrq = rowt >> 6;
        const unsigned short* src =
            smem + (wrq + wcq * 2) * 4096 + (rowt & 63) * 64 + lcq;
        int rowg = bm + rowt;
        if (rowg < M) {
            if (!OUTFP8) {
                unsigned short* C = (unsigned short*)Cout;
                *(uint4*)&C[(size_t)rowg * N + bn + lc] = *(const uint4*)src;
            } else {
                uint4 b = *(const uint4*)src;
                float f0, f1, f2, f3, f4, f5, f6, f7;
                expand2(b.x, f0, f1); expand2(b.y, f2, f3);
                expand2(b.z, f4, f5); expand2(b.w, f6, f7);
                uint2 q;
                q.x = pack4_fp8(f0, f1, f2, f3);
                q.y = pack4_fp8(f4, f5, f6, f7);
                unsigned char* C8 = (unsigned char*)Cout;
                *(uint2*)&C8[(size_t)rowg * N + bn + lc] = q;
            }
        }
    }
}

// tiny MLP; first reduces the 64 pool buckets
__global__ void k_mlp(const float* __restrict__ gb,
                      const float* __restrict__ Wf1, const float* __restrict__ bf1,
                      const float* __restrict__ Wf2, const float* __restrict__ bf2,
                      const float* __restrict__ Wf3, const float* __restrict__ bf3,
                      float* __restrict__ out) {
    __shared__ float s0[256], s1[128], s2[64];
    int t = threadIdx.x;
    float sum = 0.0f;
    for (int b = 0; b < N_BUCKETS; ++b) sum += gb[b * 256 + t];
    s0[t] = sum * (1.0f / (float)N_NODES);
    __syncthreads();
    if (t < 128) {
        float a = bf1[t];
        for (int k = 0; k < 256; ++k) a += s0[k] * Wf1[k * 128 + t];
        s1[t] = fmaxf(a, 0.0f);
    }
    __syncthreads();
    if (t < 64) {
        float a = bf2[t];
        for (int k = 0; k < 128; ++k) a += s1[k] * Wf2[k * 64 + t];
        s2[t] = fmaxf(a, 0.0f);
    }
    __syncthreads();
    if (t == 0) {
        float a = bf3[0];
        for (int k = 0; k < 64; ++k) a += s2[k] * Wf3[k];
        out[0] = a;
    }
}

extern "C" void kernel_launch(void* const* d_in, const int* in_sizes, int n_in,
                              void* d_out, int out_size, void* d_ws, size_t ws_size,
                              hipStream_t stream) {
    const float* x  = (const float*)d_in[0];
    const int* ei   = (const int*)d_in[1];
    const float* W1 = (const float*)d_in[2];
    const float* b1 = (const float*)d_in[3];
    const float* W2 = (const float*)d_in[4];
    const float* b2 = (const float*)d_in[5];
    const float* W3 = (const float*)d_in[6];
    const float* b3 = (const float*)d_in[7];
    const float* Wf1 = (const float*)d_in[8];
    const float* bf1 = (const float*)d_in[9];
    const float* Wf2 = (const float*)d_in[10];
    const float* bf2 = (const float*)d_in[11];
    const float* Wf3 = (const float*)d_in[12];
    const float* bf3 = (const float*)d_in[13];
    float* out = (float*)d_out;

    char* p = (char*)d_ws;
    auto alloc = [&](size_t bytes) {
        void* r = (void*)p;
        p += (bytes + 255) & ~((size_t)255);
        return r;
    };
    int*   cnt2    = (int*)  alloc((size_t)NC * sizeof(int));
    int*   off2    = (int*)  alloc((size_t)(NC + 1) * sizeof(int));
    int*   cursor2 = (int*)  alloc((size_t)NC * sizeof(int));
    int*   bsum2   = (int*)  alloc(CELL_NB * sizeof(int));
    int*   bbase2  = (int*)  alloc(CELL_NB * sizeof(int));
    float* dinv    = (float*)alloc(N_NODES * sizeof(float));
    int2*  epack   = (int2*) alloc((size_t)(N_EDGES + N_NODES) * sizeof(int2));
    float* gb      = (float*)alloc(N_BUCKETS * 256 * sizeof(float));
    unsigned short* W1h = (unsigned short*)alloc(128 * 256 * 2);
    unsigned short* W1l = (unsigned short*)alloc(128 * 256 * 2);
    unsigned short* W2h = (unsigned short*)alloc(256 * 512 * 2);
    unsigned short* W2l = (unsigned short*)alloc(256 * 512 * 2);
    unsigned short* W3h = (unsigned short*)alloc(512 * 256 * 2);
    unsigned short* W3l = (unsigned short*)alloc(512 * 256 * 2);
    unsigned char*  xq  = (unsigned char*) alloc((size_t)N_NODES * 128);
    unsigned short* t0  = (unsigned short*)alloc((size_t)M_PAD * 128 * 2);
    unsigned char*  h1q = (unsigned char*) alloc((size_t)N_NODES * 256);
    unsigned short* t1  = (unsigned short*)alloc((size_t)M_PAD * 256 * 2);
    unsigned short* h2  = (unsigned short*)alloc((size_t)M_PAD * 512 * 2);
    unsigned char*  t2q = (unsigned char*) alloc((size_t)N_NODES * 256);

    const int* row = ei;
    const int* col = ei + N_EDGES;

    const int NB = (N_NODES + 255) / 256;
    const int EB = (N_EDGES + 255) / 256;

    // CSR-by-(dest,slice) build + norm
    k_init2<<<CELL_NB, 256, 0, stream>>>(cnt2, gb);
    k_count2<<<EB, 256, 0, stream>>>(row, col, cnt2);
    k_self<<<NB, 256, 0, stream>>>(cnt2);
    k_dinv<<<NB, 256, 0, stream>>>(cnt2, dinv);
    k_scanA2<<<CELL_NB, 256, 0, stream>>>(cnt2, bsum2);
    k_scanB2<<<1, 256, 0, stream>>>(bsum2, bbase2);
    k_scanC2<<<CELL_NB, 256, 0, stream>>>(cnt2, bbase2, off2, cursor2);
    k_fill2<<<EB, 256, 0, stream>>>(row, col, dinv, cursor2, epack);
    k_fillself<<<NB, 256, 0, stream>>>(dinv, cursor2, epack);

    // weight prep (transpose + exact split) and x -> fp8
    k_prepW<<<(128 * 256 + 255) / 256, 256, 0, stream>>>(W1, W1h, W1l, 128, 256);
    k_prepW<<<(256 * 512 + 255) / 256, 256, 0, stream>>>(W2, W2h, W2l, 256, 512);
    k_prepW<<<(512 * 256 + 255) / 256, 256, 0, stream>>>(W3, W3h, W3l, 512, 256);
    k_prepX8<<<(N_NODES * 32 + 255) / 256, 256, 0, stream>>>(x, xq);

    const int M = N_NODES;
    const int MB = (M + 127) / 128; // 391

    // conv1: t0 = agg(x_fp8) -> bf16; h1 = relu(t0@W1 + b1) -> fp8
    k_aggp<128, 0><<<AGG_BLOCKS, 256, 0, stream>>>(
        xq, off2, epack, dinv, nullptr, t0, nullptr);
    {
        dim3 grid(MB, 256 / 128);
        k_gemm_b<1, 1, 1><<<grid, 256, 0, stream>>>(t0, W1h, W1l, b1, h1q, M, 128, 256);
    }
    // conv2: t1 = agg(h1_fp8) -> bf16; h2 = relu(t1@W2 + b2) -> bf16
    k_aggp<256, 0><<<AGG_BLOCKS, 256, 0, stream>>>(
        h1q, off2, epack, dinv, nullptr, t1, nullptr);
    {
        dim3 grid(MB, 512 / 128);
        k_gemm_b<1, 1, 0><<<grid, 256, 0, stream>>>(t1, W2h, W2l, b2, h2, M, 256, 512);
    }
    // conv3: t2 = h2@W3 -> fp8; fused agg + bias + relu + bucketed mean-pool
    {
        dim3 grid(MB, 256 / 128);
        k_gemm_b<0, 0, 1><<<grid, 256, 0, stream>>>(h2, W3h, W3l, nullptr, t2q, M, 512, 256);
    }
    k_aggp<256, 1><<<AGG_BLOCKS, 256, 0, stream>>>(
        t2q, off2, epack, dinv, b3, nullptr, gb);

    // MLP (reduces buckets internally)
    k_mlp<<<1, 256, 0, stream>>>(gb, Wf1, bf1, Wf2, bf2, Wf3, bf3, out);
}

// Round 3
// 539.570 us; speedup vs baseline: 1.1673x; 1.1673x over previous
//
#include <hip/hip_runtime.h>
#include <hip/hip_bf16.h>

#define N_NODES 50000
#define N_EDGES 800000
#define N_BUCKETS 64
#define M_PAD 50048

// ---- slice-phased aggregation geometry ------------------------------------
#define NS 8                 // source slices
#define SLICE_DIV 6250       // nodes per slice (50000/8)
#define NC (N_NODES * NS)    // 400000 (slice,dest) cells; cell = s*N + v
#define AGG_BLOCKS 1024      // persistent blocks (4 waves each)
#define DPW 13               // dests per wave: 4096*13 = 53248 >= 50000
#define INIT_NB ((NC + 255) / 256)     // 1563
#define SCAN2_NB ((NC + 1023) / 1024)  // 391 (1024 cells per scan block)

typedef short short8 __attribute__((ext_vector_type(8)));
typedef float floatx4 __attribute__((ext_vector_type(4)));
typedef float floatx2 __attribute__((ext_vector_type(2)));

// ---- bf16 helpers (RNE) ---------------------------------------------------
__device__ __forceinline__ unsigned short f2bf(float f) {
    unsigned u = __float_as_uint(f);
    unsigned r = (u + 0x7fff + ((u >> 16) & 1)) >> 16;
    return (unsigned short)r;
}
__device__ __forceinline__ float bf2f(unsigned short h) {
    return __uint_as_float(((unsigned)h) << 16);
}
__device__ __forceinline__ void expand2(unsigned u, float& lo, float& hi) {
    lo = __uint_as_float(u << 16);
    hi = __uint_as_float(u & 0xffff0000u);
}

// ---- fp8 e4m3 (OCP) HW conversion helpers ---------------------------------
__device__ __forceinline__ unsigned pack4_fp8(float f0, float f1, float f2, float f3) {
    int v = __builtin_amdgcn_cvt_pk_fp8_f32(f0, f1, 0, false);
    v = __builtin_amdgcn_cvt_pk_fp8_f32(f2, f3, v, true);
    return (unsigned)v;
}
__device__ __forceinline__ void accum_fp8x4(float* a, unsigned u, float w) {
    floatx2 lo = __builtin_amdgcn_cvt_pk_f32_fp8((int)u, false);
    floatx2 hi = __builtin_amdgcn_cvt_pk_f32_fp8((int)u, true);
    a[0] += lo[0] * w; a[1] += lo[1] * w;
    a[2] += hi[0] * w; a[3] += hi[1] * w;
}
__device__ __forceinline__ void accum_fp8x2(float* a, unsigned u, float w) {
    floatx2 lo = __builtin_amdgcn_cvt_pk_f32_fp8((int)u, false);
    a[0] += lo[0] * w; a[1] += lo[1] * w;
}

// async global->LDS, 16B per lane (GEMM staging)
__device__ __forceinline__ void gload16(const void* gp, void* lp) {
    __builtin_amdgcn_global_load_lds(
        (const __attribute__((address_space(1))) unsigned int*)gp,
        (__attribute__((address_space(3))) unsigned int*)lp,
        16, 0, 0);
}

// ---------------------------------------------------------------------------
// CSR-by-(source-slice, dest) build. cell = s*N_NODES + v.
// cnt2 pre-seeded with the self-loop (1 in the dest's own slice cell).
__global__ void k_init2(int* __restrict__ cnt2, float* __restrict__ gb) {
    int i = blockIdx.x * blockDim.x + threadIdx.x;
    if (i < NC) {
        int s = i / N_NODES;
        int v = i - s * N_NODES;
        cnt2[i] = (s == v / SLICE_DIV) ? 1 : 0;   // self-loop pre-count
    }
    if (i < N_BUCKETS * 256) gb[i] = 0.0f;
}

__global__ void k_count2(const int* __restrict__ row, const int* __restrict__ col,
                         int* __restrict__ cnt2) {
    int e = blockIdx.x * blockDim.x + threadIdx.x;
    if (e >= N_EDGES) return;
    int s = row[e] / SLICE_DIV;
    atomicAdd(&cnt2[s * N_NODES + col[e]], 1);
}

// dinv from total degree (self already pre-seeded in cnt2)
__global__ void k_dinv(const int* __restrict__ cnt2, float* __restrict__ dinv) {
    int v = blockIdx.x * blockDim.x + threadIdx.x;
    if (v >= N_NODES) return;
    int c = 0;
#pragma unroll
    for (int s = 0; s < NS; ++s) c += cnt2[s * N_NODES + v];
    dinv[v] = 1.0f / sqrtf((float)c);
}

// scan level A: per-1024-cell block sums (256 thr x int4)
__global__ __launch_bounds__(256) void k_scanA2(const int* __restrict__ cnt2,
                                                int* __restrict__ bsum) {
    __shared__ int red[256];
    int t = threadIdx.x;
    int base = blockIdx.x * 1024 + t * 4;
    int sum = 0;
    if (base + 3 < NC) {
        int4 c = *(const int4*)&cnt2[base];
        sum = c.x + c.y + c.z + c.w;
    } else {
#pragma unroll
        for (int k = 0; k < 4; ++k)
            if (base + k < NC) sum += cnt2[base + k];
    }
    red[t] = sum;
    __syncthreads();
    for (int d = 128; d > 0; d >>= 1) {
        if (t < d) red[t] += red[t + d];
        __syncthreads();
    }
    if (t == 0) bsum[blockIdx.x] = red[0];
}

// scan level B: single block over SCAN2_NB (=391) partial sums
__global__ __launch_bounds__(512) void k_scanB2(const int* __restrict__ bsum,
                                                int* __restrict__ bbase) {
    __shared__ int sc[512];
    int t = threadIdx.x;
    int v = (t < SCAN2_NB) ? bsum[t] : 0;
    sc[t] = v;
    __syncthreads();
    for (int d = 1; d < 512; d <<= 1) {
        int x = 0;
        if (t >= d) x = sc[t - d];
        __syncthreads();
        if (t >= d) sc[t] += x;
        __syncthreads();
    }
    if (t < SCAN2_NB) bbase[t] = sc[t] - v;   // exclusive
}

// scan level C: per-cell exclusive offsets (same 1024-cell tiling as A)
__global__ __launch_bounds__(256) void k_scanC2(const int* __restrict__ cnt2,
                                                const int* __restrict__ bbase,
                                                int* __restrict__ off2,
                                                int* __restrict__ cursor2) {
    __shared__ int sc[256];
    int t = threadIdx.x;
    int base = blockIdx.x * 1024 + t * 4;
    int c0 = 0, c1 = 0, c2 = 0, c3 = 0;
    if (base + 3 < NC) {
        int4 c = *(const int4*)&cnt2[base];
        c0 = c.x; c1 = c.y; c2 = c.z; c3 = c.w;
    } else {
        if (base     < NC) c0 = cnt2[base];
        if (base + 1 < NC) c1 = cnt2[base + 1];
        if (base + 2 < NC) c2 = cnt2[base + 2];
        if (base + 3 < NC) c3 = cnt2[base + 3];
    }
    int tsum = c0 + c1 + c2 + c3;
    sc[t] = tsum;
    __syncthreads();
    for (int d = 1; d < 256; d <<= 1) {
        int x = 0;
        if (t >= d) x = sc[t - d];
        __syncthreads();
        if (t >= d) sc[t] += x;
        __syncthreads();
    }
    int tex = sc[t] - tsum + bbase[blockIdx.x];
    int e0 = tex, e1 = tex + c0, e2 = e1 + c1, e3 = e2 + c2;
    if (base     < NC) { off2[base]     = e0; cursor2[base]     = e0; }
    if (base + 1 < NC) { off2[base + 1] = e1; cursor2[base + 1] = e1; }
    if (base + 2 < NC) { off2[base + 2] = e2; cursor2[base + 2] = e2; }
    if (base + 3 == NC - 1) off2[NC] = e3 + c3;   // sentinel (NC % 4 == 0)
    if (base + 3 < NC) { off2[base + 3] = e3; cursor2[base + 3] = e3; }
}

// fill edges + self-loops (fused; order within a cell is irrelevant)
__global__ void k_fill2(const int* __restrict__ row, const int* __restrict__ col,
                        const float* __restrict__ dinv, int* __restrict__ cursor2,
                        int2* __restrict__ epack) {
    int e = blockIdx.x * blockDim.x + threadIdx.x;
    if (e < N_EDGES) {
        int r = row[e];
        int s = r / SLICE_DIV;
        int p = atomicAdd(&cursor2[s * N_NODES + col[e]], 1);
        epack[p] = make_int2(r, __float_as_int(dinv[r]));
    }
    if (e < N_NODES) {
        int s = e / SLICE_DIV;
        int p = atomicAdd(&cursor2[s * N_NODES + e], 1);
        epack[p] = make_int2(e, __float_as_int(dinv[e]));
    }
}

// W [K][N] fp32 -> transposed split bf16 WT{h,l} [N][K] (weights stay exact)
__global__ void k_prepW(const float* __restrict__ W,
                        unsigned short* __restrict__ Th,
                        unsigned short* __restrict__ Tl, int K, int N) {
    int idx = blockIdx.x * blockDim.x + threadIdx.x;
    if (idx >= K * N) return;
    int n = idx / K, k = idx - n * K;
    float v = W[(size_t)k * N + n];
    unsigned short h = f2bf(v);
    Th[idx] = h;
    Tl[idx] = f2bf(v - bf2f(h));
}

// x fp32 -> fp8 e4m3; one thread per 4 features
__global__ void k_prepX8(const float* __restrict__ x, unsigned char* __restrict__ xq) {
    int i = blockIdx.x * blockDim.x + threadIdx.x;
    if (i >= N_NODES * 32) return;
    const float* s = x + (size_t)i * 4;
    *(unsigned*)&xq[(size_t)i * 4] = pack4_fp8(s[0], s[1], s[2], s[3]);
}

// ---------------------------------------------------------------------------
// Slice-phased persistent aggregation, BRANCH-FREE ZIPPER.
// Round-2 post-mortem: phasing cut L2-miss traffic 82->57.5 MB but the serial
// per-(dest,slice) loops dropped outstanding gathers to ~1/wave -> 0.49 TB/s
// service (vs the 0.9 TB/s ceiling round 0/1 saturated). This version zips
// the wave's 13 dest segments: per round, one straight-line block issues 13
// independent clamped gathers (inactive slots re-read a valid descriptor with
// weight forced to 0 -> L2 hit, no fabric cost). Zipper state is wave-uniform
// (SGPRs, scalar desc loads); accumulators per-dest in registers (static
// unroll). Cells ordered (s,v) so a wave's 13 cursors are adjacent in epack.
// POOL=0: bf16 rows out (feeds GEMM). POOL=1: bias+relu+bucketed mean-pool.
template <int DIM, int POOL>
__global__ __launch_bounds__(256) void k_aggp(
    const unsigned char* __restrict__ xq, const int* __restrict__ off2,
    const int2* __restrict__ epack, const float* __restrict__ dinv,
    const float* __restrict__ bias, unsigned short* __restrict__ outb,
    float* __restrict__ gb) {
    const int FPL = DIM / 64;   // features per lane per dest: 4 or 2
    const int wv = __builtin_amdgcn_readfirstlane(threadIdx.x >> 6);
    const int li = threadIdx.x & 63;
    const int wid = blockIdx.x * 4 + wv;
    const int d0 = wid * DPW;
    const unsigned char* __restrict__ xl = xq + li * FPL;

    float acc[DPW][FPL];
#pragma unroll
    for (int di = 0; di < DPW; ++di)
#pragma unroll
        for (int i = 0; i < FPL; ++i) acc[di][i] = 0.0f;

    for (int s = 0; s < NS; ++s) {   // slice-major sweep (the locality phase)
        int cur[DPW], end[DPW];
        int rounds = 0;
#pragma unroll
        for (int di = 0; di < DPW; ++di) {
            int v = d0 + di;
            int vc = (v < N_NODES) ? v : (N_NODES - 1);
            int cell = s * N_NODES + vc;
            int jb = off2[cell];
            int je = (v < N_NODES) ? off2[cell + 1] : jb;
            cur[di] = jb;
            end[di] = je;
            rounds = max(rounds, je - jb);
        }
        for (int r = 0; r < rounds; ++r) {
#pragma unroll
            for (int di = 0; di < DPW; ++di) {
                bool act = cur[di] < end[di];
                int jj = act ? cur[di] : (end[di] - 1);
                jj = jj < 0 ? 0 : jj;
                int2 ed = epack[jj];                    // wave-uniform (s_load)
                float w = act ? __int_as_float(ed.y) : 0.0f;
                cur[di]++;
                if constexpr (DIM == 256) {
                    unsigned gv = *(const unsigned*)&xl[(size_t)ed.x * DIM];
                    accum_fp8x4(acc[di], gv, w);
                } else {
                    unsigned gv = (unsigned)*(const unsigned short*)&xl[(size_t)ed.x * DIM];
                    accum_fp8x2(acc[di], gv, w);
                }
            }
        }
    }

    if constexpr (!POOL) {
#pragma unroll
        for (int di = 0; di < DPW; ++di) {
            int v = d0 + di;
            if (v >= N_NODES) continue;
            float dv = dinv[v];
            if constexpr (DIM == 256) {
                uint2 o;
                o.x = (unsigned)f2bf(acc[di][0] * dv) | ((unsigned)f2bf(acc[di][1] * dv) << 16);
                o.y = (unsigned)f2bf(acc[di][2] * dv) | ((unsigned)f2bf(acc[di][3] * dv) << 16);
                *(uint2*)&outb[(size_t)v * DIM + li * 4] = o;
            } else {
                unsigned o = (unsigned)f2bf(acc[di][0] * dv) | ((unsigned)f2bf(acc[di][1] * dv) << 16);
                *(unsigned*)&outb[(size_t)v * DIM + li * 2] = o;
            }
        }
    } else {
        // DIM == 256 only: relu(acc*dv + b) summed over this wave's dests
        floatx4 bv = *(const floatx4*)&bias[li * 4];
        float ps0 = 0.f, ps1 = 0.f, ps2 = 0.f, ps3 = 0.f;
#pragma unroll
        for (int di = 0; di < DPW; ++di) {
            int v = d0 + di;
            if (v >= N_NODES) continue;
            float dv = dinv[v];
            ps0 += fmaxf(acc[di][0] * dv + bv[0], 0.0f);
            ps1 += fmaxf(acc[di][1] * dv + bv[1], 0.0f);
            ps2 += fmaxf(acc[di][2] * dv + bv[2], 0.0f);
            ps3 += fmaxf(acc[di][3] * dv + bv[3], 0.0f);
        }
        float* g0 = &gb[(wid & (N_BUCKETS - 1)) * 256 + li * 4];
        atomicAdd(g0 + 0, ps0);
        atomicAdd(g0 + 1, ps1);
        atomicAdd(g0 + 2, ps2);
        atomicAdd(g0 + 3, ps3);
    }
}

// ---------------------------------------------------------------------------
// bf16-A x split-bf16-B MFMA GEMM: C = A @ (Bh+Bl) (+bias)(relu)
// B pre-transposed [N][K]. 128x128 tile, BK=32, SINGLE-buffered LDS (32KB ->
// 5 blocks/CU). LDS-staged coalesced epilogue. OUTFP8=1: fp8-e4m3 writeback.
template <int BIAS, int RELU, int OUTFP8>
__global__ __launch_bounds__(256) void k_gemm_b(
    const unsigned short* __restrict__ A,
    const unsigned short* __restrict__ Bh, const unsigned short* __restrict__ Bl,
    const float* __restrict__ bias, void* __restrict__ Cout,
    int M, int K, int N) {
    __shared__ unsigned short smem[4 * 4096];   // 32KB
    unsigned short* As  = smem;                 // 8KB
    unsigned short* BsH = smem + 4096;          // 8KB
    unsigned short* BsL = smem + 8192;          // 8KB
    int tid = threadIdx.x;
    int lane = tid & 63;
    int w = tid >> 6;
    int wr = w & 1, wc = w >> 1;
    int bm = blockIdx.x * 128, bn = blockIdx.y * 128;

    floatx4 acc[4][4];
    floatx4 zero = {0.f, 0.f, 0.f, 0.f};
#pragma unroll
    for (int t = 0; t < 4; ++t)
#pragma unroll
        for (int u = 0; u < 4; ++u) acc[t][u] = zero;

    int c0 = w * 2, c1 = c0 + 1;
    int srow = lane >> 2;
    int kg = ((lane & 3) - ((lane >> 3) & 3)) & 3;
    int kc = kg * 8;
    const unsigned short* Ap0 = A + (size_t)(bm + c0 * 16 + srow) * K + kc;
    const unsigned short* Ap1 = A + (size_t)(bm + c1 * 16 + srow) * K + kc;
    const unsigned short* Bh0 = Bh + (size_t)(bn + c0 * 16 + srow) * K + kc;
    const unsigned short* Bh1 = Bh + (size_t)(bn + c1 * 16 + srow) * K + kc;
    const unsigned short* Bl0 = Bl + (size_t)(bn + c0 * 16 + srow) * K + kc;
    const unsigned short* Bl1 = Bl + (size_t)(bn + c1 * 16 + srow) * K + kc;

    const int KT = K >> 5;
    int fr = lane & 15;
    int fq = lane >> 4;
    int cl = ((fq + (fr >> 1)) & 3) * 8;

    for (int kt = 0; kt < KT; ++kt) {
        int k0 = kt * 32;
        gload16(Ap0 + k0, As + c0 * 512);
        gload16(Ap1 + k0, As + c1 * 512);
        gload16(Bh0 + k0, BsH + c0 * 512);
        gload16(Bh1 + k0, BsH + c1 * 512);
        gload16(Bl0 + k0, BsL + c0 * 512);
        gload16(Bl1 + k0, BsL + c1 * 512);
        __syncthreads();
        short8 av[4], bhv[4], blv[4];
#pragma unroll
        for (int t = 0; t < 4; ++t) {
            av[t]  = *(const short8*)&As[(wr * 64 + t * 16 + fr) * 32 + cl];
            bhv[t] = *(const short8*)&BsH[(wc * 64 + t * 16 + fr) * 32 + cl];
            blv[t] = *(const short8*)&BsL[(wc * 64 + t * 16 + fr) * 32 + cl];
        }
#pragma unroll
        for (int t = 0; t < 4; ++t)
#pragma unroll
            for (int u = 0; u < 4; ++u) {
                acc[t][u] = __builtin_amdgcn_mfma_f32_16x16x32_bf16(av[t], bhv[u], acc[t][u], 0, 0, 0);
                acc[t][u] = __builtin_amdgcn_mfma_f32_16x16x32_bf16(av[t], blv[u], acc[t][u], 0, 0, 0);
            }
        __syncthreads();
    }

    // ---- LDS-staged epilogue (reuses all 32KB) ----
    unsigned short* cq = smem + w * 4096;
#pragma unroll
    for (int u = 0; u < 4; ++u) {
        int colq = u * 16 + fr;
        float bv = BIAS ? bias[bn + wc * 64 + colq] : 0.0f;
#pragma unroll
        for (int t = 0; t < 4; ++t) {
#pragma unroll
            for (int r = 0; r < 4; ++r) {
                float o = acc[t][u][r] + bv;
                if (RELU) o = fmaxf(o, 0.f);
                cq[(t * 16 + fq * 4 + r) * 64 + colq] = f2bf(o);
            }
        }
    }
    __syncthreads();
    int lr = tid >> 4;
    int lc = (tid & 15) * 8;
    int wcq = lc >> 6;
    int lcq = lc & 63;
#pragma unroll
    for (int i = 0; i < 8; ++i) {
        int rowt = i * 16 + lr;
        int wrq = rowt >> 6;
        const unsigned short* src =
            smem + (wrq + wcq * 2) * 4096 + (rowt & 63) * 64 + lcq;
        int rowg = bm + rowt;
        if (rowg < M) {
            if (!OUTFP8) {
                unsigned short* C = (unsigned short*)Cout;
                *(uint4*)&C[(size_t)rowg * N + bn + lc] = *(const uint4*)src;
            } else {
                uint4 b = *(const uint4*)src;
                float f0, f1, f2, f3, f4, f5, f6, f7;
                expand2(b.x, f0, f1); expand2(b.y, f2, f3);
                expand2(b.z, f4, f5); expand2(b.w, f6, f7);
                uint2 q;
                q.x = pack4_fp8(f0, f1, f2, f3);
                q.y = pack4_fp8(f4, f5, f6, f7);
                unsigned char* C8 = (unsigned char*)Cout;
                *(uint2*)&C8[(size_t)rowg * N + bn + lc] = q;
            }
        }
    }
}

// tiny MLP; first reduces the 64 pool buckets
__global__ void k_mlp(const float* __restrict__ gb,
                      const float* __restrict__ Wf1, const float* __restrict__ bf1,
                      const float* __restrict__ Wf2, const float* __restrict__ bf2,
                      const float* __restrict__ Wf3, const float* __restrict__ bf3,
                      float* __restrict__ out) {
    __shared__ float s0[256], s1[128], s2[64];
    int t = threadIdx.x;
    float sum = 0.0f;
    for (int b = 0; b < N_BUCKETS; ++b) sum += gb[b * 256 + t];
    s0[t] = sum * (1.0f / (float)N_NODES);
    __syncthreads();
    if (t < 128) {
        float a = bf1[t];
        for (int k = 0; k < 256; ++k) a += s0[k] * Wf1[k * 128 + t];
        s1[t] = fmaxf(a, 0.0f);
    }
    __syncthreads();
    if (t < 64) {
        float a = bf2[t];
        for (int k = 0; k < 128; ++k) a += s1[k] * Wf2[k * 64 + t];
        s2[t] = fmaxf(a, 0.0f);
    }
    __syncthreads();
    if (t == 0) {
        float a = bf3[0];
        for (int k = 0; k < 64; ++k) a += s2[k] * Wf3[k];
        out[0] = a;
    }
}

extern "C" void kernel_launch(void* const* d_in, const int* in_sizes, int n_in,
                              void* d_out, int out_size, void* d_ws, size_t ws_size,
                              hipStream_t stream) {
    const float* x  = (const float*)d_in[0];
    const int* ei   = (const int*)d_in[1];
    const float* W1 = (const float*)d_in[2];
    const float* b1 = (const float*)d_in[3];
    const float* W2 = (const float*)d_in[4];
    const float* b2 = (const float*)d_in[5];
    const float* W3 = (const float*)d_in[6];
    const float* b3 = (const float*)d_in[7];
    const float* Wf1 = (const float*)d_in[8];
    const float* bf1 = (const float*)d_in[9];
    const float* Wf2 = (const float*)d_in[10];
    const float* bf2 = (const float*)d_in[11];
    const float* Wf3 = (const float*)d_in[12];
    const float* bf3 = (const float*)d_in[13];
    float* out = (float*)d_out;

    char* p = (char*)d_ws;
    auto alloc = [&](size_t bytes) {
        void* r = (void*)p;
        p += (bytes + 255) & ~((size_t)255);
        return r;
    };
    int*   cnt2    = (int*)  alloc((size_t)NC * sizeof(int));
    int*   off2    = (int*)  alloc((size_t)(NC + 1) * sizeof(int));
    int*   cursor2 = (int*)  alloc((size_t)NC * sizeof(int));
    int*   bsum2   = (int*)  alloc(SCAN2_NB * sizeof(int));
    int*   bbase2  = (int*)  alloc(SCAN2_NB * sizeof(int));
    float* dinv    = (float*)alloc(N_NODES * sizeof(float));
    int2*  epack   = (int2*) alloc((size_t)(N_EDGES + N_NODES) * sizeof(int2));
    float* gb      = (float*)alloc(N_BUCKETS * 256 * sizeof(float));
    unsigned short* W1h = (unsigned short*)alloc(128 * 256 * 2);
    unsigned short* W1l = (unsigned short*)alloc(128 * 256 * 2);
    unsigned short* W2h = (unsigned short*)alloc(256 * 512 * 2);
    unsigned short* W2l = (unsigned short*)alloc(256 * 512 * 2);
    unsigned short* W3h = (unsigned short*)alloc(512 * 256 * 2);
    unsigned short* W3l = (unsigned short*)alloc(512 * 256 * 2);
    unsigned char*  xq  = (unsigned char*) alloc((size_t)N_NODES * 128);
    unsigned short* t0  = (unsigned short*)alloc((size_t)M_PAD * 128 * 2);
    unsigned char*  h1q = (unsigned char*) alloc((size_t)N_NODES * 256);
    unsigned short* t1  = (unsigned short*)alloc((size_t)M_PAD * 256 * 2);
    unsigned short* h2  = (unsigned short*)alloc((size_t)M_PAD * 512 * 2);
    unsigned char*  t2q = (unsigned char*) alloc((size_t)N_NODES * 256);

    const int* row = ei;
    const int* col = ei + N_EDGES;

    const int NB = (N_NODES + 255) / 256;
    const int EB = (N_EDGES + 255) / 256;

    // CSR-by-(slice,dest) build + norm (7 launches)
    k_init2<<<INIT_NB, 256, 0, stream>>>(cnt2, gb);
    k_count2<<<EB, 256, 0, stream>>>(row, col, cnt2);
    k_dinv<<<NB, 256, 0, stream>>>(cnt2, dinv);
    k_scanA2<<<SCAN2_NB, 256, 0, stream>>>(cnt2, bsum2);
    k_scanB2<<<1, 512, 0, stream>>>(bsum2, bbase2);
    k_scanC2<<<SCAN2_NB, 256, 0, stream>>>(cnt2, bbase2, off2, cursor2);
    k_fill2<<<EB, 256, 0, stream>>>(row, col, dinv, cursor2, epack);

    // weight prep (transpose + exact split) and x -> fp8
    k_prepW<<<(128 * 256 + 255) / 256, 256, 0, stream>>>(W1, W1h, W1l, 128, 256);
    k_prepW<<<(256 * 512 + 255) / 256, 256, 0, stream>>>(W2, W2h, W2l, 256, 512);
    k_prepW<<<(512 * 256 + 255) / 256, 256, 0, stream>>>(W3, W3h, W3l, 512, 256);
    k_prepX8<<<(N_NODES * 32 + 255) / 256, 256, 0, stream>>>(x, xq);

    const int M = N_NODES;
    const int MB = (M + 127) / 128; // 391

    // conv1: t0 = agg(x_fp8) -> bf16; h1 = relu(t0@W1 + b1) -> fp8
    k_aggp<128, 0><<<AGG_BLOCKS, 256, 0, stream>>>(
        xq, off2, epack, dinv, nullptr, t0, nullptr);
    {
        dim3 grid(MB, 256 / 128);
        k_gemm_b<1, 1, 1><<<grid, 256, 0, stream>>>(t0, W1h, W1l, b1, h1q, M, 128, 256);
    }
    // conv2: t1 = agg(h1_fp8) -> bf16; h2 = relu(t1@W2 + b2) -> bf16
    k_aggp<256, 0><<<AGG_BLOCKS, 256, 0, stream>>>(
        h1q, off2, epack, dinv, nullptr, t1, nullptr);
    {
        dim3 grid(MB, 512 / 128);
        k_gemm_b<1, 1, 0><<<grid, 256, 0, stream>>>(t1, W2h, W2l, b2, h2, M, 256, 512);
    }
    // conv3: t2 = h2@W3 -> fp8; fused agg + bias + relu + bucketed mean-pool
    {
        dim3 grid(MB, 256 / 128);
        k_gemm_b<0, 0, 1><<<grid, 256, 0, stream>>>(h2, W3h, W3l, nullptr, t2q, M, 512, 256);
    }
    k_aggp<256, 1><<<AGG_BLOCKS, 256, 0, stream>>>(
        t2q, off2, epack, dinv, b3, nullptr, gb);

    // MLP (reduces buckets internally)
    k_mlp<<<1, 256, 0, stream>>>(gb, Wf1, bf1, Wf2, bf2, Wf3, bf3, out);
}